// Round 8
// baseline (575.340 us; speedup 1.0000x reference)
//
#include <hip/hip_runtime.h>
#include <stdint.h>

#define D 128
#define K 512
#define HW 4096
#define NPIX 262144
#define OUT_NORM_ELEMS 33554432
#define MARGIN 0.005f
#define EPS 1e-12f
#define LOSCALE 2048.0f
#define RSCALE (1.0f / 2048.0f)

typedef _Float16 f16x8 __attribute__((ext_vector_type(8)));
typedef float f32x4 __attribute__((ext_vector_type(4)));

#define FENCE() asm volatile("" ::: "memory")

__device__ __forceinline__ short f2h(float f) {
    _Float16 h = (_Float16)f; return *reinterpret_cast<short*>(&h);
}
__device__ __forceinline__ float h2f(short s) {
    _Float16 h = *reinterpret_cast<_Float16*>(&s); return (float)h;
}

__global__ void zero_kernel(float* __restrict__ p, int n) {
    int i = blockIdx.x * blockDim.x + threadIdx.x;
    if (i < n) p[i] = 0.0f;
}

// One wave per centroid: fp32 normalize; store fp16 hi + 2048-scaled fp16 lo
// ([k][256] halfs: 0..127 hi, 128..255 lo'); nc = sum(c_norm^2) fp32.
__global__ void normalize_centroids(const float* __restrict__ c,
                                    short* __restrict__ csp,
                                    float* __restrict__ nc) {
    int k = blockIdx.x * 4 + (threadIdx.x >> 6);
    int lane = threadIdx.x & 63;
    float2 v = *(const float2*)(c + (size_t)k * D + lane * 2);
    float ss = v.x * v.x + v.y * v.y;
    #pragma unroll
    for (int off = 32; off; off >>= 1) ss += __shfl_xor(ss, off);
    float rinv = 1.0f / fmaxf(sqrtf(ss), EPS);
    float ox = v.x * rinv, oy = v.y * rinv;
    short hx = f2h(ox), hy = f2h(oy);
    short lx = f2h((ox - h2f(hx)) * LOSCALE);
    short ly = f2h((oy - h2f(hy)) * LOSCALE);
    *(short2*)&csp[(size_t)k * 256 + 2 * lane]       = make_short2(hx, hy);
    *(short2*)&csp[(size_t)k * 256 + 128 + 2 * lane] = make_short2(lx, ly);
    float ss2 = ox * ox + oy * oy;
    #pragma unroll
    for (int off = 32; off; off >>= 1) ss2 += __shfl_xor(ss2, off);
    if (lane == 0) nc[k] = ss2;
}

// K1: streaming normalize (round-2-proven structure). 4 px/thread, float4,
// two passes over d (second pass L3-warm). No LDS -> max occupancy.
__global__ __launch_bounds__(256) void normalize_x(
    const float* __restrict__ x, float* __restrict__ xn)
{
    int t = blockIdx.x * 256 + threadIdx.x;   // handles pixels 4t..4t+3
    int pg = t * 4;
    int b = pg >> 12;
    int pp = pg & (HW - 1);
    const float* xp = x + (size_t)b * (D * HW) + pp;

    float4 ss = make_float4(0.f, 0.f, 0.f, 0.f);
    #pragma unroll 8
    for (int d = 0; d < D; ++d) {
        float4 v = *(const float4*)(xp + (size_t)d * HW);
        ss.x += v.x * v.x; ss.y += v.y * v.y;
        ss.z += v.z * v.z; ss.w += v.w * v.w;
    }
    float4 ri = make_float4(1.f / fmaxf(sqrtf(ss.x), EPS),
                            1.f / fmaxf(sqrtf(ss.y), EPS),
                            1.f / fmaxf(sqrtf(ss.z), EPS),
                            1.f / fmaxf(sqrtf(ss.w), EPS));
    float* op = xn + (size_t)b * (D * HW) + pp;
    #pragma unroll 8
    for (int d = 0; d < D; ++d) {
        float4 v = *(const float4*)(xp + (size_t)d * HW);
        v.x *= ri.x; v.y *= ri.y; v.z *= ri.z; v.w *= ri.w;
        *(float4*)(op + (size_t)d * HW) = v;
    }
}

#define UPD(dd, cc, ri) do {                                      \
    bool lt1 = (dd) < d1[ri];                                     \
    float nd2 = lt1 ? d1[ri] : (((dd) < d2[ri]) ? (dd) : d2[ri]); \
    i1[ri] = lt1 ? (cc) : i1[ri];                                 \
    d1[ri] = lt1 ? (dd) : d1[ri];                                 \
    d2[ri] = nd2;                                                 \
} while (0)

// K2: distance GEMM + online top-2 + idx/mask. 512 thr = 8 waves x 32 px,
// 256 px/block; each wave sweeps all 512 centroids (no cross-wave merge).
// A-frags (fp16 hi + 2048-scaled lo) built from normalized f32 (L3-warm).
// LDS: B double-buffer 2x16KB (chunk = 32 centroids) + nc.
#define SMB1 16384
#define SMNC 32768
#define SM2_BYTES 34816
__global__ __launch_bounds__(512, 4) void gemm_top2(
    const float* __restrict__ xn, const short* __restrict__ csp,
    const float* __restrict__ nc, float* __restrict__ oidx,
    int* __restrict__ pixinfo)
{
    __shared__ char smem[SM2_BYTES] __attribute__((aligned(16)));
    float* nc_s = (float*)(smem + SMNC);

    const int t = threadIdx.x;
    const int lane = t & 63;
    const int wid = t >> 6;
    const int lb15 = lane & 15;
    const int kl4 = lane >> 4;
    const int kl = kl4 * 16;
    const int lswzB = (lb15 & 7) << 4;
    const int pix0 = blockIdx.x * 256;

    nc_s[t] = nc[t];

    auto stageB = [&](int bufoff, int cb) {
        const char* src = (const char*)csp + (size_t)cb * 512;
        #pragma unroll
        for (int r = 0; r < 2; ++r) {
            int P = r * 8192 + wid * 1024;       // wave-uniform LDS base
            int Pl = P + lane * 16;
            int row = Pl >> 9;
            int goff = Pl ^ ((row & 7) << 4);    // pre-swizzled source
            __builtin_amdgcn_global_load_lds(
                (const __attribute__((address_space(1))) uint32_t*)(src + goff),
                (__attribute__((address_space(3))) uint32_t*)(smem + bufoff + P),
                16, 0, 0);
        }
    };
    stageB(0, 0);

    // A fragments for 32 px/wave, from normalized f32 output
    f16x8 ahi[2][4], alo[2][4];
    #pragma unroll
    for (int mf = 0; mf < 2; ++mf) {
        int px = pix0 + wid * 32 + mf * 16 + lb15;
        const float* xp = xn + (size_t)(px >> 12) * (D * HW) + (px & (HW - 1));
        #pragma unroll
        for (int kq = 0; kq < 4; ++kq) {
            f16x8 h, l;
            #pragma unroll
            for (int e = 0; e < 8; ++e) {
                float v = xp[(size_t)(kq * 32 + kl4 * 8 + e) * HW];
                _Float16 hv = (_Float16)v;
                h[e] = hv;
                l[e] = (_Float16)((v - (float)hv) * LOSCALE);
            }
            ahi[mf][kq] = h; alo[mf][kq] = l;
        }
    }
    __syncthreads();   // nc_s visibility (full lgkmcnt drain + barrier)

    float d1[8], d2[8]; int i1[8];
    #pragma unroll
    for (int r = 0; r < 8; ++r) { d1[r] = 3.4e38f; d2[r] = 3.4e38f; i1[r] = 0; }

    for (int c = 0; c < 16; ++c) {
        const int cb = c * 32;
        const int bufoff = (c & 1) ? SMB1 : 0;
        if (c < 15) stageB((c & 1) ? 0 : SMB1, cb + 32);
        if (c < 15) { asm volatile("s_waitcnt vmcnt(2)" ::: "memory"); }
        else        { asm volatile("s_waitcnt vmcnt(0)" ::: "memory"); }
        __builtin_amdgcn_s_barrier();
        FENCE();

        f32x4 am[2][2], ac[2][2];
        #pragma unroll
        for (int mf = 0; mf < 2; ++mf)
            #pragma unroll
            for (int nf = 0; nf < 2; ++nf) {
                am[mf][nf] = (f32x4){0.f, 0.f, 0.f, 0.f};
                ac[mf][nf] = (f32x4){0.f, 0.f, 0.f, 0.f};
            }

        #pragma unroll
        for (int kq = 0; kq < 4; ++kq) {
            #pragma unroll
            for (int nf = 0; nf < 2; ++nf) {
                const int rowb = (nf * 16 + lb15) * 512;
                f16x8 bh = *(const f16x8*)(smem + bufoff + rowb + ((kq * 64 + kl) ^ lswzB));
                f16x8 bl = *(const f16x8*)(smem + bufoff + rowb + ((256 + kq * 64 + kl) ^ lswzB));
                #pragma unroll
                for (int mf = 0; mf < 2; ++mf) {
                    am[mf][nf] = __builtin_amdgcn_mfma_f32_16x16x32_f16(ahi[mf][kq], bh, am[mf][nf], 0, 0, 0);
                    ac[mf][nf] = __builtin_amdgcn_mfma_f32_16x16x32_f16(ahi[mf][kq], bl, ac[mf][nf], 0, 0, 0);
                    ac[mf][nf] = __builtin_amdgcn_mfma_f32_16x16x32_f16(alo[mf][kq], bh, ac[mf][nf], 0, 0, 0);
                }
            }
        }

        #pragma unroll
        for (int nf = 0; nf < 2; ++nf) {
            int cid = cb + nf * 16 + lb15;
            float ncv = nc_s[cid];
            #pragma unroll
            for (int mf = 0; mf < 2; ++mf)
                #pragma unroll
                for (int j = 0; j < 4; ++j) {
                    int ri = mf * 4 + j;
                    float dd = ncv - 2.f * am[mf][nf][j] - (2.f * RSCALE) * ac[mf][nf][j];
                    UPD(dd, cid, ri);
                }
        }

        FENCE();
        __builtin_amdgcn_s_barrier();
        FENCE();
    }

    // butterfly merge over the 16 centroid lanes (tie -> lower idx)
    #pragma unroll
    for (int r = 0; r < 8; ++r) {
        #pragma unroll
        for (int m = 1; m < 16; m <<= 1) {
            float o1 = __shfl_xor(d1[r], m);
            float o2 = __shfl_xor(d2[r], m);
            int   oi = __shfl_xor(i1[r], m);
            bool take = (o1 < d1[r]) || (o1 == d1[r] && oi < i1[r]);
            float loser = take ? d1[r] : o1;
            d2[r] = fminf(loser, fminf(d2[r], o2));
            if (take) { d1[r] = o1; i1[r] = oi; }
        }
    }
    if (lb15 == 0) {
        #pragma unroll
        for (int mf = 0; mf < 2; ++mf)
            #pragma unroll
            for (int j = 0; j < 4; ++j) {
                int r = mf * 4 + j;
                int px = pix0 + wid * 32 + mf * 16 + kl4 * 4 + j;
                oidx[px] = (float)i1[r];
                pixinfo[px] = (d2[r] - d1[r] > MARGIN) ? i1[r] : -1;
            }
    }
}

// K3: segment sum, no per-element atomics. 4 blocks/cluster scan pixinfo
// (L2-hot) with ballot-match and gather RAW x rows (L3-resident);
// one 128-float atomicAdd per block.
__global__ __launch_bounds__(256) void segsum_kernel(
    const float* __restrict__ x, const int* __restrict__ pixinfo,
    float* __restrict__ csum, float* __restrict__ ccnt)
{
    __shared__ float psum[4 * 128];
    __shared__ int pcnt[4];
    const int kc   = blockIdx.x >> 2;
    const int qtr  = blockIdx.x & 3;
    const int lane = threadIdx.x & 63;
    const int w    = threadIdx.x >> 6;
    const int base = qtr * 65536 + w * 16384;

    float a0 = 0.f, a1 = 0.f;
    int cnt = 0;
    for (int it = 0; it < 256; ++it) {
        int ibase = base + it * 64;
        int v = pixinfo[ibase + lane];
        unsigned long long m = __ballot(v == kc);
        cnt += (int)__popcll(m);
        while (m) {
            int bpos = __builtin_ctzll(m);
            m &= m - 1;
            int pid = ibase + bpos;
            const float* xp = x + ((size_t)(pid >> 12)) * (D * HW) + (pid & (HW - 1));
            a0 += xp[(size_t)(2 * lane) * HW];
            a1 += xp[(size_t)(2 * lane + 1) * HW];
        }
    }
    psum[w * 128 + 2 * lane]     = a0;
    psum[w * 128 + 2 * lane + 1] = a1;
    if (lane == 0) pcnt[w] = cnt;
    __syncthreads();
    if (threadIdx.x < 128) {
        float s = psum[threadIdx.x] + psum[128 + threadIdx.x] +
                  psum[256 + threadIdx.x] + psum[384 + threadIdx.x];
        atomicAdd(&csum[(size_t)kc * D + threadIdx.x], s);
    }
    if (threadIdx.x == 0) {
        float c = (float)(pcnt[0] + pcnt[1] + pcnt[2] + pcnt[3]);
        atomicAdd(&ccnt[kc], c);
    }
}

extern "C" void kernel_launch(void* const* d_in, const int* in_sizes, int n_in,
                              void* d_out, int out_size, void* d_ws, size_t ws_size,
                              hipStream_t stream) {
    const float* x   = (const float*)d_in[0];
    const float* cen = (const float*)d_in[1];

    float* out      = (float*)d_out;
    float* out_norm = out;                       // 33554432
    float* csum     = out + OUT_NORM_ELEMS;      // 512*128
    float* ccnt     = csum + (size_t)K * D;      // 512
    float* oidx     = ccnt + K;                  // 262144

    // ws footprint: 1,312,768 bytes total (proven-safe bound)
    char* ws = (char*)d_ws;
    short* csp     = (short*)ws;                 // [512][256] fp16 hi|lo' (256 KB)
    float* nc      = (float*)(ws + 262144);      // [512] f32 (2 KB)
    int*   pixinfo = (int*)(ws + 264192);        // [262144] i32 (1 MB)

    hipLaunchKernelGGL(zero_kernel, dim3((K * D + K + 255) / 256), dim3(256), 0, stream,
                       csum, K * D + K);
    hipLaunchKernelGGL(normalize_centroids, dim3(K / 4), dim3(256), 0, stream,
                       cen, csp, nc);
    hipLaunchKernelGGL(normalize_x, dim3(NPIX / 4 / 256), dim3(256), 0, stream,
                       x, out_norm);
    hipLaunchKernelGGL(gemm_top2, dim3(NPIX / 256), dim3(512), 0, stream,
                       out_norm, csp, nc, oidx, pixinfo);
    hipLaunchKernelGGL(segsum_kernel, dim3(K * 4), dim3(256), 0, stream,
                       x, pixinfo, csum, ccnt);
}

// Round 9
// 487.583 us; speedup vs baseline: 1.1800x; 1.1800x over previous
//
#include <hip/hip_runtime.h>
#include <stdint.h>

#define D 128
#define K 512
#define HW 4096
#define NPIX 262144
#define OUT_NORM_ELEMS 33554432
#define MARGIN 0.005f
#define EPS 1e-12f
#define LOSCALE 2048.0f
#define RSCALE (1.0f / 2048.0f)

typedef _Float16 f16x8 __attribute__((ext_vector_type(8)));
typedef float f32x4 __attribute__((ext_vector_type(4)));

#define FENCE() asm volatile("" ::: "memory")

__device__ __forceinline__ short f2h(float f) {
    _Float16 h = (_Float16)f; return *reinterpret_cast<short*>(&h);
}
__device__ __forceinline__ float h2f(short s) {
    _Float16 h = *reinterpret_cast<_Float16*>(&s); return (float)h;
}

__global__ void zero_kernel(float* __restrict__ p, int n) {
    int i = blockIdx.x * blockDim.x + threadIdx.x;
    if (i < n) p[i] = 0.0f;
}

// One wave per centroid: fp32 normalize; store fp16 hi + 2048-scaled fp16 lo
// ([k][256] halfs: 0..127 hi, 128..255 lo'); nc = sum(c_norm^2) fp32.
__global__ void normalize_centroids(const float* __restrict__ c,
                                    short* __restrict__ csp,
                                    float* __restrict__ nc) {
    int k = blockIdx.x * 4 + (threadIdx.x >> 6);
    int lane = threadIdx.x & 63;
    float2 v = *(const float2*)(c + (size_t)k * D + lane * 2);
    float ss = v.x * v.x + v.y * v.y;
    #pragma unroll
    for (int off = 32; off; off >>= 1) ss += __shfl_xor(ss, off);
    float rinv = 1.0f / fmaxf(sqrtf(ss), EPS);
    float ox = v.x * rinv, oy = v.y * rinv;
    short hx = f2h(ox), hy = f2h(oy);
    short lx = f2h((ox - h2f(hx)) * LOSCALE);
    short ly = f2h((oy - h2f(hy)) * LOSCALE);
    *(short2*)&csp[(size_t)k * 256 + 2 * lane]       = make_short2(hx, hy);
    *(short2*)&csp[(size_t)k * 256 + 128 + 2 * lane] = make_short2(lx, ly);
    float ss2 = ox * ox + oy * oy;
    #pragma unroll
    for (int off = 32; off; off >>= 1) ss2 += __shfl_xor(ss2, off);
    if (lane == 0) nc[k] = ss2;
}

// K1: streaming normalize. 4 px/thread, float4, two passes over d
// (second pass L3-warm). No LDS -> max occupancy.
__global__ __launch_bounds__(256) void normalize_x(
    const float* __restrict__ x, float* __restrict__ xn)
{
    int t = blockIdx.x * 256 + threadIdx.x;   // handles pixels 4t..4t+3
    int pg = t * 4;
    int b = pg >> 12;
    int pp = pg & (HW - 1);
    const float* xp = x + (size_t)b * (D * HW) + pp;

    float4 ss = make_float4(0.f, 0.f, 0.f, 0.f);
    #pragma unroll 8
    for (int d = 0; d < D; ++d) {
        float4 v = *(const float4*)(xp + (size_t)d * HW);
        ss.x += v.x * v.x; ss.y += v.y * v.y;
        ss.z += v.z * v.z; ss.w += v.w * v.w;
    }
    float4 ri = make_float4(1.f / fmaxf(sqrtf(ss.x), EPS),
                            1.f / fmaxf(sqrtf(ss.y), EPS),
                            1.f / fmaxf(sqrtf(ss.z), EPS),
                            1.f / fmaxf(sqrtf(ss.w), EPS));
    float* op = xn + (size_t)b * (D * HW) + pp;
    #pragma unroll 8
    for (int d = 0; d < D; ++d) {
        float4 v = *(const float4*)(xp + (size_t)d * HW);
        v.x *= ri.x; v.y *= ri.y; v.z *= ri.z; v.w *= ri.w;
        *(float4*)(op + (size_t)d * HW) = v;
    }
}

#define UPD(dd, cc, ri) do {                                      \
    bool lt1 = (dd) < d1[ri];                                     \
    float nd2 = lt1 ? d1[ri] : (((dd) < d2[ri]) ? (dd) : d2[ri]); \
    i1[ri] = lt1 ? (cc) : i1[ri];                                 \
    d1[ri] = lt1 ? (dd) : d1[ri];                                 \
    d2[ri] = nd2;                                                 \
} while (0)

// K2: distance GEMM + online top-2 + idx/mask. 512 thr = 8 waves x 32 px,
// 256 px/block; each wave sweeps all 512 centroids (no cross-wave merge).
// A-frags (fp16 hi + 2048-scaled lo) built from normalized f32 (L3-warm).
// LDS: B double-buffer 2x16KB (chunk = 32 centroids) + nc.
#define SMB1 16384
#define SMNC 32768
#define SM2_BYTES 34816
__global__ __launch_bounds__(512, 4) void gemm_top2(
    const float* __restrict__ xn, const short* __restrict__ csp,
    const float* __restrict__ nc, float* __restrict__ oidx,
    int* __restrict__ pixinfo)
{
    __shared__ char smem[SM2_BYTES] __attribute__((aligned(16)));
    float* nc_s = (float*)(smem + SMNC);

    const int t = threadIdx.x;
    const int lane = t & 63;
    const int wid = t >> 6;
    const int lb15 = lane & 15;
    const int kl4 = lane >> 4;
    const int kl = kl4 * 16;
    const int lswzB = (lb15 & 7) << 4;
    const int pix0 = blockIdx.x * 256;

    nc_s[t] = nc[t];

    auto stageB = [&](int bufoff, int cb) {
        const char* src = (const char*)csp + (size_t)cb * 512;
        #pragma unroll
        for (int r = 0; r < 2; ++r) {
            int P = r * 8192 + wid * 1024;       // wave-uniform LDS base
            int Pl = P + lane * 16;
            int row = Pl >> 9;
            int goff = Pl ^ ((row & 7) << 4);    // pre-swizzled source
            __builtin_amdgcn_global_load_lds(
                (const __attribute__((address_space(1))) uint32_t*)(src + goff),
                (__attribute__((address_space(3))) uint32_t*)(smem + bufoff + P),
                16, 0, 0);
        }
    };
    stageB(0, 0);

    // A fragments for 32 px/wave, from normalized f32 output
    f16x8 ahi[2][4], alo[2][4];
    #pragma unroll
    for (int mf = 0; mf < 2; ++mf) {
        int px = pix0 + wid * 32 + mf * 16 + lb15;
        const float* xp = xn + (size_t)(px >> 12) * (D * HW) + (px & (HW - 1));
        #pragma unroll
        for (int kq = 0; kq < 4; ++kq) {
            f16x8 h, l;
            #pragma unroll
            for (int e = 0; e < 8; ++e) {
                float v = xp[(size_t)(kq * 32 + kl4 * 8 + e) * HW];
                _Float16 hv = (_Float16)v;
                h[e] = hv;
                l[e] = (_Float16)((v - (float)hv) * LOSCALE);
            }
            ahi[mf][kq] = h; alo[mf][kq] = l;
        }
    }
    __syncthreads();   // nc_s visibility (full lgkmcnt drain + barrier)

    float d1[8], d2[8]; int i1[8];
    #pragma unroll
    for (int r = 0; r < 8; ++r) { d1[r] = 3.4e38f; d2[r] = 3.4e38f; i1[r] = 0; }

    for (int c = 0; c < 16; ++c) {
        const int cb = c * 32;
        const int bufoff = (c & 1) ? SMB1 : 0;
        if (c < 15) stageB((c & 1) ? 0 : SMB1, cb + 32);
        if (c < 15) { asm volatile("s_waitcnt vmcnt(2)" ::: "memory"); }
        else        { asm volatile("s_waitcnt vmcnt(0)" ::: "memory"); }
        __builtin_amdgcn_s_barrier();
        FENCE();

        f32x4 am[2][2], ac[2][2];
        #pragma unroll
        for (int mf = 0; mf < 2; ++mf)
            #pragma unroll
            for (int nf = 0; nf < 2; ++nf) {
                am[mf][nf] = (f32x4){0.f, 0.f, 0.f, 0.f};
                ac[mf][nf] = (f32x4){0.f, 0.f, 0.f, 0.f};
            }

        #pragma unroll
        for (int kq = 0; kq < 4; ++kq) {
            #pragma unroll
            for (int nf = 0; nf < 2; ++nf) {
                const int rowb = (nf * 16 + lb15) * 512;
                f16x8 bh = *(const f16x8*)(smem + bufoff + rowb + ((kq * 64 + kl) ^ lswzB));
                f16x8 bl = *(const f16x8*)(smem + bufoff + rowb + ((256 + kq * 64 + kl) ^ lswzB));
                #pragma unroll
                for (int mf = 0; mf < 2; ++mf) {
                    am[mf][nf] = __builtin_amdgcn_mfma_f32_16x16x32_f16(ahi[mf][kq], bh, am[mf][nf], 0, 0, 0);
                    ac[mf][nf] = __builtin_amdgcn_mfma_f32_16x16x32_f16(ahi[mf][kq], bl, ac[mf][nf], 0, 0, 0);
                    ac[mf][nf] = __builtin_amdgcn_mfma_f32_16x16x32_f16(alo[mf][kq], bh, ac[mf][nf], 0, 0, 0);
                }
            }
        }

        #pragma unroll
        for (int nf = 0; nf < 2; ++nf) {
            int cid = cb + nf * 16 + lb15;
            float ncv = nc_s[cid];
            #pragma unroll
            for (int mf = 0; mf < 2; ++mf)
                #pragma unroll
                for (int j = 0; j < 4; ++j) {
                    int ri = mf * 4 + j;
                    float dd = ncv - 2.f * am[mf][nf][j] - (2.f * RSCALE) * ac[mf][nf][j];
                    UPD(dd, cid, ri);
                }
        }

        FENCE();
        __builtin_amdgcn_s_barrier();
        FENCE();
    }

    // butterfly merge over the 16 centroid lanes (tie -> lower idx)
    #pragma unroll
    for (int r = 0; r < 8; ++r) {
        #pragma unroll
        for (int m = 1; m < 16; m <<= 1) {
            float o1 = __shfl_xor(d1[r], m);
            float o2 = __shfl_xor(d2[r], m);
            int   oi = __shfl_xor(i1[r], m);
            bool take = (o1 < d1[r]) || (o1 == d1[r] && oi < i1[r]);
            float loser = take ? d1[r] : o1;
            d2[r] = fminf(loser, fminf(d2[r], o2));
            if (take) { d1[r] = o1; i1[r] = oi; }
        }
    }
    if (lb15 == 0) {
        #pragma unroll
        for (int mf = 0; mf < 2; ++mf)
            #pragma unroll
            for (int j = 0; j < 4; ++j) {
                int r = mf * 4 + j;
                int px = pix0 + wid * 32 + mf * 16 + kl4 * 4 + j;
                oidx[px] = (float)i1[r];
                pixinfo[px] = (d2[r] - d1[r] > MARGIN) ? i1[r] : -1;
            }
    }
}

// K3: d-sliced coalesced segment sum. Grid = 32 d-groups x 8 pixel-chunks.
// Each block: 4 d-planes x 32768 pixels; coalesced x dword loads; LDS f32
// bins[4][512] via ds_add; flush = 2048 global atomics/block (0.5M total).
// Counts computed by the dg==0 blocks via LDS int bins.
__global__ __launch_bounds__(512) void segsum_kernel(
    const float* __restrict__ x, const int* __restrict__ pixinfo,
    float* __restrict__ csum, float* __restrict__ ccnt)
{
    __shared__ float bins[4 * 512];
    __shared__ int cbin[512];
    const int dg = blockIdx.x >> 3;      // 0..31 -> d = dg*4 .. dg*4+3
    const int ch = blockIdx.x & 7;       // 0..7  -> px chunk of 32768
    const int t  = threadIdx.x;
    const int d0 = dg * 4;

    #pragma unroll
    for (int i = 0; i < 4; ++i) bins[i * 512 + t] = 0.f;
    if (t < 512) cbin[t] = 0;
    __syncthreads();

    const int base = ch * 32768;
    for (int it = 0; it < 64; ++it) {
        int pxi = base + it * 512 + t;
        int v = pixinfo[pxi];
        if (v >= 0) {
            const float* xp = x + (size_t)(pxi >> 12) * (D * HW)
                                + (size_t)d0 * HW + (pxi & (HW - 1));
            atomicAdd(&bins[0 * 512 + v], xp[0]);
            atomicAdd(&bins[1 * 512 + v], xp[HW]);
            atomicAdd(&bins[2 * 512 + v], xp[2 * HW]);
            atomicAdd(&bins[3 * 512 + v], xp[3 * HW]);
            if (dg == 0) atomicAdd(&cbin[v], 1);
        }
    }
    __syncthreads();

    #pragma unroll
    for (int i = 0; i < 4; ++i) {
        int idx = i * 512 + t;           // idx = d-sub * 512 + cluster
        int dd  = idx >> 9;
        int kc  = idx & 511;
        float s = bins[dd * 512 + kc];
        if (s != 0.f) atomicAdd(&csum[(size_t)kc * D + d0 + dd], s);
    }
    if (dg == 0 && t < 512 && cbin[t] > 0)
        atomicAdd(&ccnt[t], (float)cbin[t]);
}

extern "C" void kernel_launch(void* const* d_in, const int* in_sizes, int n_in,
                              void* d_out, int out_size, void* d_ws, size_t ws_size,
                              hipStream_t stream) {
    const float* x   = (const float*)d_in[0];
    const float* cen = (const float*)d_in[1];

    float* out      = (float*)d_out;
    float* out_norm = out;                       // 33554432
    float* csum     = out + OUT_NORM_ELEMS;      // 512*128
    float* ccnt     = csum + (size_t)K * D;      // 512
    float* oidx     = ccnt + K;                  // 262144

    // ws footprint: 1,312,768 bytes total (proven-safe bound)
    char* ws = (char*)d_ws;
    short* csp     = (short*)ws;                 // [512][256] fp16 hi|lo' (256 KB)
    float* nc      = (float*)(ws + 262144);      // [512] f32 (2 KB)
    int*   pixinfo = (int*)(ws + 264192);        // [262144] i32 (1 MB)

    hipLaunchKernelGGL(zero_kernel, dim3((K * D + K + 255) / 256), dim3(256), 0, stream,
                       csum, K * D + K);
    hipLaunchKernelGGL(normalize_centroids, dim3(K / 4), dim3(256), 0, stream,
                       cen, csp, nc);
    hipLaunchKernelGGL(normalize_x, dim3(NPIX / 4 / 256), dim3(256), 0, stream,
                       x, out_norm);
    hipLaunchKernelGGL(gemm_top2, dim3(NPIX / 256), dim3(512), 0, stream,
                       out_norm, csp, nc, oidx, pixinfo);
    hipLaunchKernelGGL(segsum_kernel, dim3(256), dim3(512), 0, stream,
                       x, pixinfo, csum, ccnt);
}

// Round 10
// 467.936 us; speedup vs baseline: 1.2295x; 1.0420x over previous
//
#include <hip/hip_runtime.h>
#include <stdint.h>

#define D 128
#define K 512
#define HW 4096
#define NPIX 262144
#define OUT_NORM_ELEMS 33554432
#define MARGIN 0.005f
#define EPS 1e-12f
#define LOSCALE 2048.0f
#define RSCALE (1.0f / 2048.0f)

typedef _Float16 f16x8 __attribute__((ext_vector_type(8)));
typedef float f32x4 __attribute__((ext_vector_type(4)));

#define FENCE() asm volatile("" ::: "memory")

__device__ __forceinline__ short f2h(float f) {
    _Float16 h = (_Float16)f; return *reinterpret_cast<short*>(&h);
}
__device__ __forceinline__ float h2f(short s) {
    _Float16 h = *reinterpret_cast<_Float16*>(&s); return (float)h;
}

__global__ void zero_kernel(float* __restrict__ p, int n) {
    int i = blockIdx.x * blockDim.x + threadIdx.x;
    if (i < n) p[i] = 0.0f;
}

// One wave per centroid: fp32 normalize; store fp16 hi + 2048-scaled fp16 lo
// ([k][256] halfs: 0..127 hi, 128..255 lo'); nc = sum(c_norm^2) fp32.
__global__ void normalize_centroids(const float* __restrict__ c,
                                    short* __restrict__ csp,
                                    float* __restrict__ nc) {
    int k = blockIdx.x * 4 + (threadIdx.x >> 6);
    int lane = threadIdx.x & 63;
    float2 v = *(const float2*)(c + (size_t)k * D + lane * 2);
    float ss = v.x * v.x + v.y * v.y;
    #pragma unroll
    for (int off = 32; off; off >>= 1) ss += __shfl_xor(ss, off);
    float rinv = 1.0f / fmaxf(sqrtf(ss), EPS);
    float ox = v.x * rinv, oy = v.y * rinv;
    short hx = f2h(ox), hy = f2h(oy);
    short lx = f2h((ox - h2f(hx)) * LOSCALE);
    short ly = f2h((oy - h2f(hy)) * LOSCALE);
    *(short2*)&csp[(size_t)k * 256 + 2 * lane]       = make_short2(hx, hy);
    *(short2*)&csp[(size_t)k * 256 + 128 + 2 * lane] = make_short2(lx, ly);
    float ss2 = ox * ox + oy * oy;
    #pragma unroll
    for (int off = 32; off; off >>= 1) ss2 += __shfl_xor(ss2, off);
    if (lane == 0) nc[k] = ss2;
}

// K1: streaming normalize. 4 px/thread, float4, two passes over d
// (second pass L3-warm). No LDS -> max occupancy.
__global__ __launch_bounds__(256) void normalize_x(
    const float* __restrict__ x, float* __restrict__ xn)
{
    int t = blockIdx.x * 256 + threadIdx.x;   // handles pixels 4t..4t+3
    int pg = t * 4;
    int b = pg >> 12;
    int pp = pg & (HW - 1);
    const float* xp = x + (size_t)b * (D * HW) + pp;

    float4 ss = make_float4(0.f, 0.f, 0.f, 0.f);
    #pragma unroll 8
    for (int d = 0; d < D; ++d) {
        float4 v = *(const float4*)(xp + (size_t)d * HW);
        ss.x += v.x * v.x; ss.y += v.y * v.y;
        ss.z += v.z * v.z; ss.w += v.w * v.w;
    }
    float4 ri = make_float4(1.f / fmaxf(sqrtf(ss.x), EPS),
                            1.f / fmaxf(sqrtf(ss.y), EPS),
                            1.f / fmaxf(sqrtf(ss.z), EPS),
                            1.f / fmaxf(sqrtf(ss.w), EPS));
    float* op = xn + (size_t)b * (D * HW) + pp;
    #pragma unroll 8
    for (int d = 0; d < D; ++d) {
        float4 v = *(const float4*)(xp + (size_t)d * HW);
        v.x *= ri.x; v.y *= ri.y; v.z *= ri.z; v.w *= ri.w;
        *(float4*)(op + (size_t)d * HW) = v;
    }
}

#define UPD(dd, cc, ri) do {                                      \
    bool lt1 = (dd) < d1[ri];                                     \
    float nd2 = lt1 ? d1[ri] : (((dd) < d2[ri]) ? (dd) : d2[ri]); \
    i1[ri] = lt1 ? (cc) : i1[ri];                                 \
    d1[ri] = lt1 ? (dd) : d1[ri];                                 \
    d2[ri] = nd2;                                                 \
} while (0)

// K2: distance GEMM + online top-2 + idx/mask. 512 thr = 8 waves x 32 px,
// 256 px/block; each wave sweeps all 512 centroids.
// Schedule: 4-deep LDS ring buffer, ONE barrier per 32-centroid chunk,
// counted vmcnt(4) (prefetch depth 2, never drained until the tail).
#define SMBUF 16384
#define SMNC  65536
#define SM2_BYTES 67584
__global__ __launch_bounds__(512, 4) void gemm_top2(
    const float* __restrict__ xn, const short* __restrict__ csp,
    const float* __restrict__ nc, float* __restrict__ oidx,
    int* __restrict__ pixinfo)
{
    __shared__ char smem[SM2_BYTES] __attribute__((aligned(16)));
    float* nc_s = (float*)(smem + SMNC);

    const int t = threadIdx.x;
    const int lane = t & 63;
    const int wid = t >> 6;
    const int lb15 = lane & 15;
    const int kl4 = lane >> 4;
    const int kl = kl4 * 16;
    const int lswzB = (lb15 & 7) << 4;
    const int pix0 = blockIdx.x * 256;

    nc_s[t] = nc[t];

    auto stageB = [&](int bufoff, int cb) {
        const char* src = (const char*)csp + (size_t)cb * 512;
        #pragma unroll
        for (int r = 0; r < 2; ++r) {
            int P = r * 8192 + wid * 1024;       // wave-uniform LDS base
            int Pl = P + lane * 16;
            int row = Pl >> 9;
            int goff = Pl ^ ((row & 7) << 4);    // pre-swizzled source
            __builtin_amdgcn_global_load_lds(
                (const __attribute__((address_space(1))) uint32_t*)(src + goff),
                (__attribute__((address_space(3))) uint32_t*)(smem + bufoff + P),
                16, 0, 0);
        }
    };

    // A fragments for 32 px/wave, from normalized f32 output (L3-warm)
    f16x8 ahi[2][4], alo[2][4];
    #pragma unroll
    for (int mf = 0; mf < 2; ++mf) {
        int px = pix0 + wid * 32 + mf * 16 + lb15;
        const float* xp = xn + (size_t)(px >> 12) * (D * HW) + (px & (HW - 1));
        #pragma unroll
        for (int kq = 0; kq < 4; ++kq) {
            f16x8 h, l;
            #pragma unroll
            for (int e = 0; e < 8; ++e) {
                float v = xp[(size_t)(kq * 32 + kl4 * 8 + e) * HW];
                _Float16 hv = (_Float16)v;
                h[e] = hv;
                l[e] = (_Float16)((v - (float)hv) * LOSCALE);
            }
            ahi[mf][kq] = h; alo[mf][kq] = l;
        }
    }
    __syncthreads();   // nc_s visibility (drains everything; prefetch not yet issued)

    stageB(0 * SMBUF, 0);     // chunk 0
    stageB(1 * SMBUF, 32);    // chunk 1

    float d1[8], d2[8]; int i1[8];
    #pragma unroll
    for (int r = 0; r < 8; ++r) { d1[r] = 3.4e38f; d2[r] = 3.4e38f; i1[r] = 0; }

    for (int c = 0; c < 16; ++c) {
        const int cb = c * 32;
        if (c + 2 < 16) stageB(((c + 2) & 3) * SMBUF, cb + 64);
        if (c < 14)      { asm volatile("s_waitcnt vmcnt(4)" ::: "memory"); }
        else if (c == 14){ asm volatile("s_waitcnt vmcnt(2)" ::: "memory"); }
        else             { asm volatile("s_waitcnt vmcnt(0)" ::: "memory"); }
        __builtin_amdgcn_s_barrier();
        FENCE();
        const int bufoff = (c & 3) * SMBUF;

        f32x4 am[2][2], ac[2][2];
        #pragma unroll
        for (int mf = 0; mf < 2; ++mf)
            #pragma unroll
            for (int nf = 0; nf < 2; ++nf) {
                am[mf][nf] = (f32x4){0.f, 0.f, 0.f, 0.f};
                ac[mf][nf] = (f32x4){0.f, 0.f, 0.f, 0.f};
            }

        #pragma unroll
        for (int kq = 0; kq < 4; ++kq) {
            #pragma unroll
            for (int nf = 0; nf < 2; ++nf) {
                const int rowb = (nf * 16 + lb15) * 512;
                f16x8 bh = *(const f16x8*)(smem + bufoff + rowb + ((kq * 64 + kl) ^ lswzB));
                f16x8 bl = *(const f16x8*)(smem + bufoff + rowb + ((256 + kq * 64 + kl) ^ lswzB));
                #pragma unroll
                for (int mf = 0; mf < 2; ++mf) {
                    am[mf][nf] = __builtin_amdgcn_mfma_f32_16x16x32_f16(ahi[mf][kq], bh, am[mf][nf], 0, 0, 0);
                    ac[mf][nf] = __builtin_amdgcn_mfma_f32_16x16x32_f16(ahi[mf][kq], bl, ac[mf][nf], 0, 0, 0);
                    ac[mf][nf] = __builtin_amdgcn_mfma_f32_16x16x32_f16(alo[mf][kq], bh, ac[mf][nf], 0, 0, 0);
                }
            }
        }

        #pragma unroll
        for (int nf = 0; nf < 2; ++nf) {
            int cid = cb + nf * 16 + lb15;
            float ncv = nc_s[cid];
            #pragma unroll
            for (int mf = 0; mf < 2; ++mf)
                #pragma unroll
                for (int j = 0; j < 4; ++j) {
                    int ri = mf * 4 + j;
                    float dd = ncv - 2.f * am[mf][nf][j] - (2.f * RSCALE) * ac[mf][nf][j];
                    UPD(dd, cid, ri);
                }
        }
        FENCE();
    }

    // butterfly merge over the 16 centroid lanes (tie -> lower idx)
    #pragma unroll
    for (int r = 0; r < 8; ++r) {
        #pragma unroll
        for (int m = 1; m < 16; m <<= 1) {
            float o1 = __shfl_xor(d1[r], m);
            float o2 = __shfl_xor(d2[r], m);
            int   oi = __shfl_xor(i1[r], m);
            bool take = (o1 < d1[r]) || (o1 == d1[r] && oi < i1[r]);
            float loser = take ? d1[r] : o1;
            d2[r] = fminf(loser, fminf(d2[r], o2));
            if (take) { d1[r] = o1; i1[r] = oi; }
        }
    }
    if (lb15 == 0) {
        #pragma unroll
        for (int mf = 0; mf < 2; ++mf)
            #pragma unroll
            for (int j = 0; j < 4; ++j) {
                int r = mf * 4 + j;
                int px = pix0 + wid * 32 + mf * 16 + kl4 * 4 + j;
                oidx[px] = (float)i1[r];
                pixinfo[px] = (d2[r] - d1[r] > MARGIN) ? i1[r] : -1;
            }
    }
}

// K3: d-sliced coalesced segment sum. Grid = 32 d-groups x 8 pixel-chunks.
// Each block: 4 d-planes x 32768 pixels; coalesced x dword loads; LDS f32
// bins[4][512] via ds_add; flush = 2048 global atomics/block (0.5M total).
__global__ __launch_bounds__(512) void segsum_kernel(
    const float* __restrict__ x, const int* __restrict__ pixinfo,
    float* __restrict__ csum, float* __restrict__ ccnt)
{
    __shared__ float bins[4 * 512];
    __shared__ int cbin[512];
    const int dg = blockIdx.x >> 3;      // 0..31 -> d = dg*4 .. dg*4+3
    const int ch = blockIdx.x & 7;       // 0..7  -> px chunk of 32768
    const int t  = threadIdx.x;
    const int d0 = dg * 4;

    #pragma unroll
    for (int i = 0; i < 4; ++i) bins[i * 512 + t] = 0.f;
    if (t < 512) cbin[t] = 0;
    __syncthreads();

    const int base = ch * 32768;
    for (int it = 0; it < 64; ++it) {
        int pxi = base + it * 512 + t;
        int v = pixinfo[pxi];
        if (v >= 0) {
            const float* xp = x + (size_t)(pxi >> 12) * (D * HW)
                                + (size_t)d0 * HW + (pxi & (HW - 1));
            atomicAdd(&bins[0 * 512 + v], xp[0]);
            atomicAdd(&bins[1 * 512 + v], xp[HW]);
            atomicAdd(&bins[2 * 512 + v], xp[2 * HW]);
            atomicAdd(&bins[3 * 512 + v], xp[3 * HW]);
            if (dg == 0) atomicAdd(&cbin[v], 1);
        }
    }
    __syncthreads();

    #pragma unroll
    for (int i = 0; i < 4; ++i) {
        int idx = i * 512 + t;           // idx = d-sub * 512 + cluster
        int dd  = idx >> 9;
        int kc  = idx & 511;
        float s = bins[dd * 512 + kc];
        if (s != 0.f) atomicAdd(&csum[(size_t)kc * D + d0 + dd], s);
    }
    if (dg == 0 && t < 512 && cbin[t] > 0)
        atomicAdd(&ccnt[t], (float)cbin[t]);
}

extern "C" void kernel_launch(void* const* d_in, const int* in_sizes, int n_in,
                              void* d_out, int out_size, void* d_ws, size_t ws_size,
                              hipStream_t stream) {
    const float* x   = (const float*)d_in[0];
    const float* cen = (const float*)d_in[1];

    float* out      = (float*)d_out;
    float* out_norm = out;                       // 33554432
    float* csum     = out + OUT_NORM_ELEMS;      // 512*128
    float* ccnt     = csum + (size_t)K * D;      // 512
    float* oidx     = ccnt + K;                  // 262144

    // ws footprint: 1,312,768 bytes total (proven-safe bound)
    char* ws = (char*)d_ws;
    short* csp     = (short*)ws;                 // [512][256] fp16 hi|lo' (256 KB)
    float* nc      = (float*)(ws + 262144);      // [512] f32 (2 KB)
    int*   pixinfo = (int*)(ws + 264192);        // [262144] i32 (1 MB)

    hipLaunchKernelGGL(zero_kernel, dim3((K * D + K + 255) / 256), dim3(256), 0, stream,
                       csum, K * D + K);
    hipLaunchKernelGGL(normalize_centroids, dim3(K / 4), dim3(256), 0, stream,
                       cen, csp, nc);
    hipLaunchKernelGGL(normalize_x, dim3(NPIX / 4 / 256), dim3(256), 0, stream,
                       x, out_norm);
    hipLaunchKernelGGL(gemm_top2, dim3(NPIX / 256), dim3(512), 0, stream,
                       out_norm, csp, nc, oidx, pixinfo);
    hipLaunchKernelGGL(segsum_kernel, dim3(256), dim3(512), 0, stream,
                       x, pixinfo, csum, ccnt);
}